// Round 5
// baseline (242.377 us; speedup 1.0000x reference)
//
#include <hip/hip_runtime.h>

static constexpr int NB = 4;    // batch
static constexpr int L  = 256;  // Lx == Lm
static constexpr int D  = 256;
static constexpr unsigned GRID = 512;

__device__ __forceinline__ float fast_rcp(float x) {
#if __has_builtin(__builtin_amdgcn_rcpf)
    return __builtin_amdgcn_rcpf(x);
#else
    return 1.0f / x;
#endif
}

__device__ __forceinline__ float fast_exp(float x) {   // e^x
#if __has_builtin(__builtin_amdgcn_exp2f)
    return __builtin_amdgcn_exp2f(x * 1.4426950408889634f);
#else
    return __expf(x);
#endif
}

__device__ __forceinline__ float exp_2x(float x) {     // e^(2x)
#if __has_builtin(__builtin_amdgcn_exp2f)
    return __builtin_amdgcn_exp2f(x * 2.8853900817779268f);
#else
    return __expf(2.0f * x);
#endif
}

// tanh(a+b) given e = exp(2a)*exp(2b):  tanh = 1 - 2/(e+1)
__device__ __forceinline__ float tanh_from_e(float e) {
    return fmaf(-2.0f, fast_rcp(e + 1.0f), 1.0f);
}

// Device-scope grid barrier. Counter must be zeroed (hipMemsetAsync) per call.
// Safe because grid (512) == exactly the co-resident capacity enforced by
// __launch_bounds__(256,2) + 65 KB LDS (2 blocks/CU x 256 CUs).
__device__ __forceinline__ void grid_barrier(unsigned* ctr) {
    __threadfence();                       // release (device scope)
    __syncthreads();
    if (threadIdx.x == 0) {
        atomicAdd(ctr, 1u);
        while (__hip_atomic_load(ctr, __ATOMIC_RELAXED, __HIP_MEMORY_SCOPE_AGENT) < GRID)
            __builtin_amdgcn_s_sleep(8);
    }
    __syncthreads();
    __threadfence();                       // acquire
}

// ---------------------------------------------------------------------------
// Fused persistent kernel: P1 linear+exp -> barrier -> P2 score -> barrier ->
// P3 both attentions.  512 blocks x 256 threads, 2 blocks/CU everywhere.
// ---------------------------------------------------------------------------
__global__ __launch_bounds__(256, 2) void fused_kernel(
    const float* __restrict__ x, const float* __restrict__ mem,
    const int* __restrict__ mask,
    const float* __restrict__ w1, const float* __restrict__ b1,
    const float* __restrict__ w2, const float* __restrict__ wst,
    float* __restrict__ out, float* __restrict__ Smask, float* __restrict__ agg,
    float* __restrict__ E1, float* __restrict__ E2, float* __restrict__ ST,
    unsigned* __restrict__ bar)
{
    __shared__ __align__(16) char smem[66560];   // max over phases (P1: 65 KB)
    const int t   = threadIdx.x;
    const int bid = blockIdx.x;

    // ===================== Phase 1: E = exp(2*(src@W^T + b)) =================
    {
        float4* xs4 = reinterpret_cast<float4*>(smem);          // 32*65 float4
        float4* ws4 = xs4 + 32 * 65;                            // 32*65 float4
        const int rb  = (bid >> 3) * 32;      // 0..2047
        const int cb  = (bid & 7) * 32;
        const int which = rb >= 1024;
        const int rloc  = which ? rb - 1024 : rb;
        const float* src = which ? mem : x;
        const float* W   = which ? w2  : w1;
        float*       dst = which ? E2  : E1;

        const float4* src4 = reinterpret_cast<const float4*>(src) + rloc * 64;
        const float4* Wg4  = reinterpret_cast<const float4*>(W)   + cb   * 64;
#pragma unroll
        for (int k = 0; k < 8; ++k) {
            int idx = k * 256 + t;
            int r = idx >> 6, c = idx & 63;
            xs4[r * 65 + c] = src4[r * 64 + c];
            ws4[r * 65 + c] = Wg4[r * 64 + c];
        }
        __syncthreads();

        const int rr = t >> 4, cc = t & 15;
        const float4* a0p = xs4 + rr * 65;
        const float4* a1p = xs4 + (rr + 16) * 65;
        const float4* w0p = ws4 + cc * 65;
        const float4* w1p = ws4 + (cc + 16) * 65;
        float acc00 = 0.f, acc01 = 0.f, acc10 = 0.f, acc11 = 0.f;
#pragma unroll 4
        for (int d4 = 0; d4 < 64; ++d4) {
            float4 a0 = a0p[d4], a1 = a1p[d4];
            float4 w0 = w0p[d4], w1 = w1p[d4];
            acc00 = fmaf(a0.x, w0.x, acc00); acc00 = fmaf(a0.y, w0.y, acc00);
            acc00 = fmaf(a0.z, w0.z, acc00); acc00 = fmaf(a0.w, w0.w, acc00);
            acc01 = fmaf(a0.x, w1.x, acc01); acc01 = fmaf(a0.y, w1.y, acc01);
            acc01 = fmaf(a0.z, w1.z, acc01); acc01 = fmaf(a0.w, w1.w, acc01);
            acc10 = fmaf(a1.x, w0.x, acc10); acc10 = fmaf(a1.y, w0.y, acc10);
            acc10 = fmaf(a1.z, w0.z, acc10); acc10 = fmaf(a1.w, w0.w, acc10);
            acc11 = fmaf(a1.x, w1.x, acc11); acc11 = fmaf(a1.y, w1.y, acc11);
            acc11 = fmaf(a1.z, w1.z, acc11); acc11 = fmaf(a1.w, w1.w, acc11);
        }
        const float bias0 = which ? 0.f : b1[cb + cc];
        const float bias1 = which ? 0.f : b1[cb + cc + 16];
        dst[(rloc + rr)      * D + cb + cc]      = exp_2x(acc00 + bias0);
        dst[(rloc + rr)      * D + cb + cc + 16] = exp_2x(acc01 + bias1);
        dst[(rloc + rr + 16) * D + cb + cc]      = exp_2x(acc10 + bias0);
        dst[(rloc + rr + 16) * D + cb + cc + 16] = exp_2x(acc11 + bias1);
    }

    grid_barrier(bar);

    // ===================== Phase 2: score (16x x 32m tile per block) =========
    {
        float4* s1    = reinterpret_cast<float4*>(smem);        // 16*65 float4
        float4* s2    = s1 + 16 * 65;                           // 32*65 float4
        float*  stile = reinterpret_cast<float*>(s2 + 32 * 65); // 32*17 floats

        const int b  = bid >> 7;
        const int r7 = bid & 127;
        const int xt = (r7 >> 3) * 16;       // 16 x-tiles
        const int mt = (r7 & 7) * 32;        // 8 m-tiles

        const float4* e14 = reinterpret_cast<const float4*>(E1) + (b * L + xt) * 64;
        const float4* e24 = reinterpret_cast<const float4*>(E2) + (b * L + mt) * 64;
#pragma unroll
        for (int k = 0; k < 4; ++k) {
            int idx = k * 256 + t;
            int r = idx >> 6, c = idx & 63;
            s1[r * 65 + c] = e14[r * 64 + c];
        }
#pragma unroll
        for (int k = 0; k < 8; ++k) {
            int idx = k * 256 + t;
            int r = idx >> 6, c = idx & 63;
            s2[r * 65 + c] = e24[r * 64 + c];
        }
        __syncthreads();

        const int rr = t >> 4, cc = t & 15;  // x-row rr, m-rows {cc, cc+16}
        const float4* ap  = s1 + rr * 65;
        const float4* b0p = s2 + cc * 65;
        const float4* b1p = s2 + (cc + 16) * 65;
        const float4* w4  = reinterpret_cast<const float4*>(wst);  // uniform
        float acc0 = 0.f, acc1 = 0.f;
#pragma unroll 4
        for (int d4 = 0; d4 < 64; ++d4) {
            float4 a  = ap[d4];
            float4 b0 = b0p[d4], b1 = b1p[d4];
            float4 w  = w4[d4];
            acc0 = fmaf(tanh_from_e(a.x * b0.x), w.x, acc0);
            acc0 = fmaf(tanh_from_e(a.y * b0.y), w.y, acc0);
            acc0 = fmaf(tanh_from_e(a.z * b0.z), w.z, acc0);
            acc0 = fmaf(tanh_from_e(a.w * b0.w), w.w, acc0);
            acc1 = fmaf(tanh_from_e(a.x * b1.x), w.x, acc1);
            acc1 = fmaf(tanh_from_e(a.y * b1.y), w.y, acc1);
            acc1 = fmaf(tanh_from_e(a.z * b1.z), w.z, acc1);
            acc1 = fmaf(tanh_from_e(a.w * b1.w), w.w, acc1);
        }

        const int x0 = xt + rr, m0 = mt + cc, m1 = mt + cc + 16;
        const bool k0 = (mask[b * L + m0] == 0), k1 = (mask[b * L + m1] == 0);
        Smask[((b * L + x0) << 8) + m0] = k0 ? -1e30f : acc0;
        Smask[((b * L + x0) << 8) + m1] = k1 ? -1e30f : acc1;

        stile[cc        * 17 + rr] = acc0;   // transpose tile [32 m][16 x]
        stile[(cc + 16) * 17 + rr] = acc1;
        __syncthreads();
#pragma unroll
        for (int k = 0; k < 2; ++k) {
            int idx = k * 256 + t;
            int mr = idx >> 4, xc = idx & 15;
            ST[((b * L + mt + mr) << 8) + xt + xc] = stile[mr * 17 + xc];
        }
    }

    grid_barrier(bar + 32);

    // ===================== Phase 3: both attentions ==========================
    {
        float*  p    = reinterpret_cast<float*>(smem);            // [4][256]
        float4* part = reinterpret_cast<float4*>(smem + 4096);    // [4][4][64]

        int abid = bid;
        const float* S; const float* V; float* o;
        if (abid < NB * L / 4) { S = Smask; V = mem; o = out; }
        else                   { S = ST;    V = x;   o = agg; abid -= NB * L / 4; }

        const int row0 = abid * 4;
        const int b    = row0 >> 8;
        const int w    = t >> 6, l = t & 63;

        // wave-local softmax: wave w owns row row0+w, lane l owns m=4l..4l+3
        {
            float4 sv = reinterpret_cast<const float4*>(S)[((row0 + w) << 6) + l];
            float m = fmaxf(fmaxf(sv.x, sv.y), fmaxf(sv.z, sv.w));
#pragma unroll
            for (int off = 32; off; off >>= 1) m = fmaxf(m, __shfl_xor(m, off));
            float e0 = fast_exp(sv.x - m), e1 = fast_exp(sv.y - m);
            float e2 = fast_exp(sv.z - m), e3 = fast_exp(sv.w - m);
            float s = (e0 + e1) + (e2 + e3);
#pragma unroll
            for (int off = 32; off; off >>= 1) s += __shfl_xor(s, off);
            float rs = fast_rcp(s);
            reinterpret_cast<float4*>(p + w * L)[l] =
                make_float4(e0 * rs, e1 * rs, e2 * rs, e3 * rs);
        }
        __syncthreads();

        // P @ V: wave w covers m in [64w, 64w+64), lane l owns d4=l
        const float4* V4 = reinterpret_cast<const float4*>(V) + (b * L) * 64;
        float4 acc[4];
#pragma unroll
        for (int r = 0; r < 4; ++r) acc[r] = make_float4(0.f, 0.f, 0.f, 0.f);

#pragma unroll 2
        for (int k4 = 0; k4 < 16; ++k4) {
            const int m0 = w * 64 + k4 * 4;
            float4 v0 = V4[(m0 + 0) * 64 + l];
            float4 v1 = V4[(m0 + 1) * 64 + l];
            float4 v2 = V4[(m0 + 2) * 64 + l];
            float4 v3 = V4[(m0 + 3) * 64 + l];
#pragma unroll
            for (int r = 0; r < 4; ++r) {
                float4 pr = *reinterpret_cast<const float4*>(p + r * L + m0);
                acc[r].x = fmaf(pr.x, v0.x, acc[r].x); acc[r].y = fmaf(pr.x, v0.y, acc[r].y);
                acc[r].z = fmaf(pr.x, v0.z, acc[r].z); acc[r].w = fmaf(pr.x, v0.w, acc[r].w);
                acc[r].x = fmaf(pr.y, v1.x, acc[r].x); acc[r].y = fmaf(pr.y, v1.y, acc[r].y);
                acc[r].z = fmaf(pr.y, v1.z, acc[r].z); acc[r].w = fmaf(pr.y, v1.w, acc[r].w);
                acc[r].x = fmaf(pr.z, v2.x, acc[r].x); acc[r].y = fmaf(pr.z, v2.y, acc[r].y);
                acc[r].z = fmaf(pr.z, v2.z, acc[r].z); acc[r].w = fmaf(pr.z, v2.w, acc[r].w);
                acc[r].x = fmaf(pr.w, v3.x, acc[r].x); acc[r].y = fmaf(pr.w, v3.y, acc[r].y);
                acc[r].z = fmaf(pr.w, v3.z, acc[r].z); acc[r].w = fmaf(pr.w, v3.w, acc[r].w);
            }
        }
#pragma unroll
        for (int r = 0; r < 4; ++r) part[(r * 4 + w) * 64 + l] = acc[r];
        __syncthreads();

        {   // wave w reduces row row0+w
            float4 r0 = part[(w * 4 + 0) * 64 + l], r1 = part[(w * 4 + 1) * 64 + l];
            float4 r2 = part[(w * 4 + 2) * 64 + l], r3 = part[(w * 4 + 3) * 64 + l];
            float4 ov;
            ov.x = (r0.x + r1.x) + (r2.x + r3.x);
            ov.y = (r0.y + r1.y) + (r2.y + r3.y);
            ov.z = (r0.z + r1.z) + (r2.z + r3.z);
            ov.w = (r0.w + r1.w) + (r2.w + r3.w);
            reinterpret_cast<float4*>(o)[((row0 + w) << 6) + l] = ov;
        }
    }
}

extern "C" void kernel_launch(void* const* d_in, const int* in_sizes, int n_in,
                              void* d_out, int out_size, void* d_ws, size_t ws_size,
                              hipStream_t stream)
{
    const float* x    = (const float*)d_in[0];  // [4,256,256]
    const float* mem  = (const float*)d_in[1];  // [4,256,256]
    const int*   mask = (const int*)  d_in[2];  // [4,256]
    const float* w1   = (const float*)d_in[3];  // [256,256]
    const float* b1   = (const float*)d_in[4];  // [256]
    const float* w2   = (const float*)d_in[5];  // [256,256]
    const float* wst  = (const float*)d_in[6];  // [256]

    float* out   = (float*)d_out;               // [4,256,256]
    float* Smask = out + NB * L * L;            // [4,256,256] (masked S, output 1)
    float* agg   = Smask + NB * L * L;          // [4,256,256] (agg_2_h, output 2)

    float* E1 = (float*)d_ws;                   // [4,256,256] exp(2*i1)
    float* E2 = E1 + NB * L * D;                // [4,256,256] exp(2*i2)
    float* ST = E2 + NB * L * D;                // [4,256,256] unmasked S^T
    unsigned* bar = (unsigned*)(ST + NB * L * D);  // 2 counters, 128B apart

    hipMemsetAsync(bar, 0, 256, stream);        // zero barrier counters (capturable)
    fused_kernel<<<GRID, 256, 0, stream>>>(x, mem, mask, w1, b1, w2, wst,
                                           out, Smask, agg, E1, E2, ST, bar);
}

// Round 6
// 42.816 us; speedup vs baseline: 5.6609x; 5.6609x over previous
//
#include <hip/hip_runtime.h>

static constexpr int NB = 4;    // batch
static constexpr int L  = 256;  // Lx == Lm
static constexpr int D  = 256;

__device__ __forceinline__ float fast_rcp(float x) {
#if __has_builtin(__builtin_amdgcn_rcpf)
    return __builtin_amdgcn_rcpf(x);
#else
    return 1.0f / x;
#endif
}

__device__ __forceinline__ float fast_exp(float x) {   // e^x
#if __has_builtin(__builtin_amdgcn_exp2f)
    return __builtin_amdgcn_exp2f(x * 1.4426950408889634f);
#else
    return __expf(x);
#endif
}

__device__ __forceinline__ float exp_2x(float x) {     // e^(2x)
#if __has_builtin(__builtin_amdgcn_exp2f)
    return __builtin_amdgcn_exp2f(x * 2.8853900817779268f);
#else
    return __expf(2.0f * x);
#endif
}

// tanh(a+b) given e = exp(2a)*exp(2b):  tanh = 1 - 2/(e+1)
__device__ __forceinline__ float tanh_from_e(float e) {
    return fmaf(-2.0f, fast_rcp(e + 1.0f), 1.0f);
}

// ---------------------------------------------------------------------------
// K1: tiled GEMM for both linears; writes E = exp(2*(src@W^T+b)) in X-layout:
//   EX (as float4)[d4 * 1024 + (b*L + row)] = { E[row, 4*d4 .. 4*d4+3] }
// Row space 0..1023 -> E1X (x,W1,b1); 1024..2047 -> E2X (mem,W2).
// ---------------------------------------------------------------------------
__global__ __launch_bounds__(256) void linear_kernel(
    const float* __restrict__ x, const float* __restrict__ mem,
    const float* __restrict__ w1, const float* __restrict__ b1,
    const float* __restrict__ w2,
    float* __restrict__ E1X, float* __restrict__ E2X)
{
    const int bid = blockIdx.x;           // 512 blocks: 64 rowgroups x 8 colgroups
    const int rb  = (bid >> 3) * 32;      // 0..2047
    const int cb  = (bid & 7) * 32;
    const int which = rb >= 1024;
    const int rloc  = which ? rb - 1024 : rb;   // 0..1023 == b*L + row
    const float* src = which ? mem : x;
    const float* W   = which ? w2  : w1;
    float*       dstX = which ? E2X : E1X;

    constexpr int P4 = 65;                // float4 per LDS row (260 floats)
    __shared__ __align__(16) float4 xs4[32 * P4];
    __shared__ __align__(16) float4 ws4[32 * P4];

    const int t = threadIdx.x;
    const float4* src4 = reinterpret_cast<const float4*>(src) + rloc * 64;
    const float4* Wg4  = reinterpret_cast<const float4*>(W)   + cb   * 64;
#pragma unroll
    for (int k = 0; k < 8; ++k) {
        int idx = k * 256 + t;            // one full 1KB row per wave-instr
        int r = idx >> 6, c = idx & 63;
        xs4[r * P4 + c] = src4[r * 64 + c];
        ws4[r * P4 + c] = Wg4[r * 64 + c];
    }
    __syncthreads();

    const int rr = t >> 4, cc = t & 15;   // rows {rr, rr+16}, cols {cc, cc+16}
    const float4* a0p = xs4 + rr * P4;
    const float4* a1p = xs4 + (rr + 16) * P4;
    const float4* w0p = ws4 + cc * P4;
    const float4* w1p = ws4 + (cc + 16) * P4;
    float acc00 = 0.f, acc01 = 0.f, acc10 = 0.f, acc11 = 0.f;
#pragma unroll 4
    for (int d4 = 0; d4 < 64; ++d4) {
        float4 a0 = a0p[d4], a1 = a1p[d4];
        float4 w0 = w0p[d4], w1 = w1p[d4];
        acc00 = fmaf(a0.x, w0.x, acc00); acc00 = fmaf(a0.y, w0.y, acc00);
        acc00 = fmaf(a0.z, w0.z, acc00); acc00 = fmaf(a0.w, w0.w, acc00);
        acc01 = fmaf(a0.x, w1.x, acc01); acc01 = fmaf(a0.y, w1.y, acc01);
        acc01 = fmaf(a0.z, w1.z, acc01); acc01 = fmaf(a0.w, w1.w, acc01);
        acc10 = fmaf(a1.x, w0.x, acc10); acc10 = fmaf(a1.y, w0.y, acc10);
        acc10 = fmaf(a1.z, w0.z, acc10); acc10 = fmaf(a1.w, w0.w, acc10);
        acc11 = fmaf(a1.x, w1.x, acc11); acc11 = fmaf(a1.y, w1.y, acc11);
        acc11 = fmaf(a1.z, w1.z, acc11); acc11 = fmaf(a1.w, w1.w, acc11);
    }
    const float bias0 = which ? 0.f : b1[cb + cc];
    const float bias1 = which ? 0.f : b1[cb + cc + 16];
    const float e00 = exp_2x(acc00 + bias0);   // (rA, c0)
    const float e01 = exp_2x(acc01 + bias1);   // (rA, c1)
    const float e10 = exp_2x(acc10 + bias0);   // (rB, c0)
    const float e11 = exp_2x(acc11 + bias1);   // (rB, c1)
    const int c0 = cb + cc, c1 = cb + cc + 16;
    const int rA = rloc + rr, rB = rloc + rr + 16;
    dstX[((c0 >> 2) * 1024 + rA) * 4 + (c0 & 3)] = e00;
    dstX[((c1 >> 2) * 1024 + rA) * 4 + (c1 & 3)] = e01;
    dstX[((c0 >> 2) * 1024 + rB) * 4 + (c0 & 3)] = e10;
    dstX[((c1 >> 2) * 1024 + rB) * 4 + (c1 & 3)] = e11;
}

// ---------------------------------------------------------------------------
// K2: fused score + softmax + PV.  512 blocks:
//   ROW blocks (bid<256): b, x0=(bid&63)*4. Thread t owns m-column t.
//     S[x0..x0+3][t] computed in regs -> write Smask -> masked softmax -> @mem -> out
//   COL blocks: b, m0. Thread t owns x-column t. Recompute S^T strip (unmasked)
//     -> softmax over x -> @x -> agg.   (ST never materialized)
// Per-lane E via coalesced float4 (X layout); strip E + wst via uniform loads.
// ---------------------------------------------------------------------------
__global__ __launch_bounds__(256) void fused2_kernel(
    const float* __restrict__ x, const float* __restrict__ mem,
    const int* __restrict__ mask, const float* __restrict__ wst,
    const float* __restrict__ E1X, const float* __restrict__ E2X,
    float* __restrict__ out, float* __restrict__ Smask, float* __restrict__ agg)
{
    int bid = blockIdx.x;
    const bool isRow = bid < 256;
    if (!isRow) bid -= 256;
    const int b    = bid >> 6;
    const int r0   = (bid & 63) * 4;     // x0 (ROW) or m0 (COL)
    const int base = b * L;              // 0,256,512,768
    const int t    = threadIdx.x;

    const float4* laneE  = reinterpret_cast<const float4*>(isRow ? E2X : E1X);
    const float4* stripE = reinterpret_cast<const float4*>(isRow ? E1X : E2X);
    const float4* w4     = reinterpret_cast<const float4*>(wst);

    // ---- score: acc[r] = S[strip-row r][lane-col t] ----
    float acc0 = 0.f, acc1 = 0.f, acc2 = 0.f, acc3 = 0.f;
#pragma unroll 4
    for (int d4 = 0; d4 < 64; ++d4) {
        const int plane = d4 * 1024 + base;
        float4 ev = laneE[plane + t];         // coalesced per-lane
        float4 s0 = stripE[plane + r0];       // uniform -> s_load
        float4 s1 = stripE[plane + r0 + 1];
        float4 s2 = stripE[plane + r0 + 2];
        float4 s3 = stripE[plane + r0 + 3];
        float4 w  = w4[d4];
        acc0 = fmaf(tanh_from_e(ev.x * s0.x), w.x, acc0);
        acc0 = fmaf(tanh_from_e(ev.y * s0.y), w.y, acc0);
        acc0 = fmaf(tanh_from_e(ev.z * s0.z), w.z, acc0);
        acc0 = fmaf(tanh_from_e(ev.w * s0.w), w.w, acc0);
        acc1 = fmaf(tanh_from_e(ev.x * s1.x), w.x, acc1);
        acc1 = fmaf(tanh_from_e(ev.y * s1.y), w.y, acc1);
        acc1 = fmaf(tanh_from_e(ev.z * s1.z), w.z, acc1);
        acc1 = fmaf(tanh_from_e(ev.w * s1.w), w.w, acc1);
        acc2 = fmaf(tanh_from_e(ev.x * s2.x), w.x, acc2);
        acc2 = fmaf(tanh_from_e(ev.y * s2.y), w.y, acc2);
        acc2 = fmaf(tanh_from_e(ev.z * s2.z), w.z, acc2);
        acc2 = fmaf(tanh_from_e(ev.w * s2.w), w.w, acc2);
        acc3 = fmaf(tanh_from_e(ev.x * s3.x), w.x, acc3);
        acc3 = fmaf(tanh_from_e(ev.y * s3.y), w.y, acc3);
        acc3 = fmaf(tanh_from_e(ev.z * s3.z), w.z, acc3);
        acc3 = fmaf(tanh_from_e(ev.w * s3.w), w.w, acc3);
    }

    __shared__ __align__(16) float sS[4][L];          // scores, then p (in place)
    __shared__ __align__(16) float4 part[4][4][64];

    if (isRow) {
        const bool dead = (mask[base + t] == 0);
        const float v0 = dead ? -1e30f : acc0;
        const float v1 = dead ? -1e30f : acc1;
        const float v2 = dead ? -1e30f : acc2;
        const float v3 = dead ? -1e30f : acc3;
        Smask[((base + r0 + 0) << 8) + t] = v0;       // S output (masked)
        Smask[((base + r0 + 1) << 8) + t] = v1;
        Smask[((base + r0 + 2) << 8) + t] = v2;
        Smask[((base + r0 + 3) << 8) + t] = v3;
        sS[0][t] = v0; sS[1][t] = v1; sS[2][t] = v2; sS[3][t] = v3;
    } else {
        sS[0][t] = acc0; sS[1][t] = acc1; sS[2][t] = acc2; sS[3][t] = acc3;
    }
    __syncthreads();

    // ---- wave-local softmax: wave w owns strip-row w, lane l owns 4l..4l+3 ----
    const int w = t >> 6, l = t & 63;
    {
        float4 sv = reinterpret_cast<const float4*>(sS[w])[l];
        float m = fmaxf(fmaxf(sv.x, sv.y), fmaxf(sv.z, sv.w));
#pragma unroll
        for (int o = 32; o; o >>= 1) m = fmaxf(m, __shfl_xor(m, o));
        float e0 = fast_exp(sv.x - m), e1 = fast_exp(sv.y - m);
        float e2 = fast_exp(sv.z - m), e3 = fast_exp(sv.w - m);
        float s = (e0 + e1) + (e2 + e3);
#pragma unroll
        for (int o = 32; o; o >>= 1) s += __shfl_xor(s, o);
        float rs = fast_rcp(s);
        reinterpret_cast<float4*>(sS[w])[l] =
            make_float4(e0 * rs, e1 * rs, e2 * rs, e3 * rs);   // p, in place
    }
    __syncthreads();

    // ---- P @ V: wave w covers k in [64w,64w+64), lane l owns d4=l ----
    const float4* V4 = reinterpret_cast<const float4*>(isRow ? mem : x) + base * 64;
    float4 acc[4];
#pragma unroll
    for (int r = 0; r < 4; ++r) acc[r] = make_float4(0.f, 0.f, 0.f, 0.f);

#pragma unroll 2
    for (int k4 = 0; k4 < 16; ++k4) {
        const int m0 = w * 64 + k4 * 4;
        float4 v0 = V4[(m0 + 0) * 64 + l];
        float4 v1 = V4[(m0 + 1) * 64 + l];
        float4 v2 = V4[(m0 + 2) * 64 + l];
        float4 v3 = V4[(m0 + 3) * 64 + l];
#pragma unroll
        for (int r = 0; r < 4; ++r) {
            float4 pr = *reinterpret_cast<const float4*>(&sS[r][m0]);
            acc[r].x = fmaf(pr.x, v0.x, acc[r].x); acc[r].y = fmaf(pr.x, v0.y, acc[r].y);
            acc[r].z = fmaf(pr.x, v0.z, acc[r].z); acc[r].w = fmaf(pr.x, v0.w, acc[r].w);
            acc[r].x = fmaf(pr.y, v1.x, acc[r].x); acc[r].y = fmaf(pr.y, v1.y, acc[r].y);
            acc[r].z = fmaf(pr.y, v1.z, acc[r].z); acc[r].w = fmaf(pr.y, v1.w, acc[r].w);
            acc[r].x = fmaf(pr.z, v2.x, acc[r].x); acc[r].y = fmaf(pr.z, v2.y, acc[r].y);
            acc[r].z = fmaf(pr.z, v2.z, acc[r].z); acc[r].w = fmaf(pr.z, v2.w, acc[r].w);
            acc[r].x = fmaf(pr.w, v3.x, acc[r].x); acc[r].y = fmaf(pr.w, v3.y, acc[r].y);
            acc[r].z = fmaf(pr.w, v3.z, acc[r].z); acc[r].w = fmaf(pr.w, v3.w, acc[r].w);
        }
    }
#pragma unroll
    for (int r = 0; r < 4; ++r) part[r][w][l] = acc[r];
    __syncthreads();

    {   // wave w reduces strip-row w and writes
        float4 q0 = part[w][0][l], q1 = part[w][1][l];
        float4 q2 = part[w][2][l], q3 = part[w][3][l];
        float4 ov;
        ov.x = (q0.x + q1.x) + (q2.x + q3.x);
        ov.y = (q0.y + q1.y) + (q2.y + q3.y);
        ov.z = (q0.z + q1.z) + (q2.z + q3.z);
        ov.w = (q0.w + q1.w) + (q2.w + q3.w);
        float* o = isRow ? out : agg;
        reinterpret_cast<float4*>(o)[((base + r0 + w) << 6) + l] = ov;
    }
}

extern "C" void kernel_launch(void* const* d_in, const int* in_sizes, int n_in,
                              void* d_out, int out_size, void* d_ws, size_t ws_size,
                              hipStream_t stream)
{
    const float* x    = (const float*)d_in[0];  // [4,256,256]
    const float* mem  = (const float*)d_in[1];  // [4,256,256]
    const int*   mask = (const int*)  d_in[2];  // [4,256]
    const float* w1   = (const float*)d_in[3];  // [256,256]
    const float* b1   = (const float*)d_in[4];  // [256]
    const float* w2   = (const float*)d_in[5];  // [256,256]
    const float* wst  = (const float*)d_in[6];  // [256]

    float* out   = (float*)d_out;               // [4,256,256]
    float* Smask = out + NB * L * L;            // [4,256,256] (masked S, output 1)
    float* agg   = Smask + NB * L * L;          // [4,256,256] (agg_2_h, output 2)

    float* E1X = (float*)d_ws;                  // 1 MB, X-layout exp(2*i1)
    float* E2X = E1X + NB * L * D;              // 1 MB, X-layout exp(2*i2)

    linear_kernel<<<512, 256, 0, stream>>>(x, mem, w1, b1, w2, E1X, E2X);
    fused2_kernel<<<512, 256, 0, stream>>>(x, mem, mask, wst, E1X, E2X,
                                           out, Smask, agg);
}

// Round 7
// 41.702 us; speedup vs baseline: 5.8121x; 1.0267x over previous
//
#include <hip/hip_runtime.h>

static constexpr int NB = 4;    // batch
static constexpr int L  = 256;  // Lx == Lm
static constexpr int D  = 256;

__device__ __forceinline__ float fast_rcp(float x) {
#if __has_builtin(__builtin_amdgcn_rcpf)
    return __builtin_amdgcn_rcpf(x);
#else
    return 1.0f / x;
#endif
}

__device__ __forceinline__ float fast_exp(float x) {   // e^x
#if __has_builtin(__builtin_amdgcn_exp2f)
    return __builtin_amdgcn_exp2f(x * 1.4426950408889634f);
#else
    return __expf(x);
#endif
}

__device__ __forceinline__ float exp_2x(float x) {     // e^(2x)
#if __has_builtin(__builtin_amdgcn_exp2f)
    return __builtin_amdgcn_exp2f(x * 2.8853900817779268f);
#else
    return __expf(2.0f * x);
#endif
}

// ---------------------------------------------------------------------------
// K1: tiled GEMM for both linears; writes E = exp(2*(src@W^T+b)) in TWO
// layouts:  X-layout  EX(as float4)[d4*1024 + (b*L+row)] = E[row,4d4..4d4+3]
//           row-major ER[row*256 + col]
// Row space 0..1023 -> E1 (x,W1,b1); 1024..2047 -> E2 (mem,W2).
// ---------------------------------------------------------------------------
__global__ __launch_bounds__(256) void linear_kernel(
    const float* __restrict__ x, const float* __restrict__ mem,
    const float* __restrict__ w1, const float* __restrict__ b1,
    const float* __restrict__ w2,
    float* __restrict__ E1X, float* __restrict__ E2X,
    float* __restrict__ E1R, float* __restrict__ E2R)
{
    const int bid = blockIdx.x;           // 512 blocks: 64 rowgroups x 8 colgroups
    const int rb  = (bid >> 3) * 32;      // 0..2047
    const int cb  = (bid & 7) * 32;
    const int which = rb >= 1024;
    const int rloc  = which ? rb - 1024 : rb;   // 0..1023 == b*L + row
    const float* src = which ? mem : x;
    const float* W   = which ? w2  : w1;
    float* dstX = which ? E2X : E1X;
    float* dstR = which ? E2R : E1R;

    constexpr int P4 = 65;                // float4 per LDS row (260 floats)
    __shared__ __align__(16) float4 xs4[32 * P4];
    __shared__ __align__(16) float4 ws4[32 * P4];

    const int t = threadIdx.x;
    const float4* src4 = reinterpret_cast<const float4*>(src) + rloc * 64;
    const float4* Wg4  = reinterpret_cast<const float4*>(W)   + cb   * 64;
#pragma unroll
    for (int k = 0; k < 8; ++k) {
        int idx = k * 256 + t;            // one full 1KB row per wave-instr
        int r = idx >> 6, c = idx & 63;
        xs4[r * P4 + c] = src4[r * 64 + c];
        ws4[r * P4 + c] = Wg4[r * 64 + c];
    }
    __syncthreads();

    const int rr = t >> 4, cc = t & 15;   // rows {rr, rr+16}, cols {cc, cc+16}
    const float4* a0p = xs4 + rr * P4;
    const float4* a1p = xs4 + (rr + 16) * P4;
    const float4* w0p = ws4 + cc * P4;
    const float4* w1p = ws4 + (cc + 16) * P4;
    float acc00 = 0.f, acc01 = 0.f, acc10 = 0.f, acc11 = 0.f;
#pragma unroll 4
    for (int d4 = 0; d4 < 64; ++d4) {
        float4 a0 = a0p[d4], a1 = a1p[d4];
        float4 w0 = w0p[d4], w1 = w1p[d4];
        acc00 = fmaf(a0.x, w0.x, acc00); acc00 = fmaf(a0.y, w0.y, acc00);
        acc00 = fmaf(a0.z, w0.z, acc00); acc00 = fmaf(a0.w, w0.w, acc00);
        acc01 = fmaf(a0.x, w1.x, acc01); acc01 = fmaf(a0.y, w1.y, acc01);
        acc01 = fmaf(a0.z, w1.z, acc01); acc01 = fmaf(a0.w, w1.w, acc01);
        acc10 = fmaf(a1.x, w0.x, acc10); acc10 = fmaf(a1.y, w0.y, acc10);
        acc10 = fmaf(a1.z, w0.z, acc10); acc10 = fmaf(a1.w, w0.w, acc10);
        acc11 = fmaf(a1.x, w1.x, acc11); acc11 = fmaf(a1.y, w1.y, acc11);
        acc11 = fmaf(a1.z, w1.z, acc11); acc11 = fmaf(a1.w, w1.w, acc11);
    }
    const float bias0 = which ? 0.f : b1[cb + cc];
    const float bias1 = which ? 0.f : b1[cb + cc + 16];
    const float e00 = exp_2x(acc00 + bias0);   // (rA, c0)
    const float e01 = exp_2x(acc01 + bias1);   // (rA, c1)
    const float e10 = exp_2x(acc10 + bias0);   // (rB, c0)
    const float e11 = exp_2x(acc11 + bias1);   // (rB, c1)
    const int c0 = cb + cc, c1 = cb + cc + 16;
    const int rA = rloc + rr, rB = rloc + rr + 16;
    dstX[((c0 >> 2) * 1024 + rA) * 4 + (c0 & 3)] = e00;
    dstX[((c1 >> 2) * 1024 + rA) * 4 + (c1 & 3)] = e01;
    dstX[((c0 >> 2) * 1024 + rB) * 4 + (c0 & 3)] = e10;
    dstX[((c1 >> 2) * 1024 + rB) * 4 + (c1 & 3)] = e11;
    dstR[rA * D + c0] = e00;
    dstR[rA * D + c1] = e01;
    dstR[rB * D + c0] = e10;
    dstR[rB * D + c1] = e11;
}

// ---------------------------------------------------------------------------
// K2: fused score + softmax + PV.  512 blocks:
//   ROW (bid<256): strip = 4 x-rows, lane t owns m-col t -> Smask + out
//   COL          : strip = 4 m-rows, lane t owns x-col t -> agg
// Strip E + wst staged in LDS (broadcast reads); lane E via X-layout float4.
// tanh term: acc += w * rcp(fma(ev,s,1));  S = W_tot - 2*acc.
// Softmax max-free (|S|<=~10); 1/rowsum folded into final store.
// ---------------------------------------------------------------------------
__global__ __launch_bounds__(256) void fused2_kernel(
    const float* __restrict__ x, const float* __restrict__ mem,
    const int* __restrict__ mask, const float* __restrict__ wst,
    const float* __restrict__ E1X, const float* __restrict__ E2X,
    const float* __restrict__ E1R, const float* __restrict__ E2R,
    float* __restrict__ out, float* __restrict__ Smask, float* __restrict__ agg)
{
    int bid = blockIdx.x;
    const bool isRow = bid < 256;
    if (!isRow) bid -= 256;
    const int b    = bid >> 6;
    const int r0   = (bid & 63) * 4;     // x0 (ROW) or m0 (COL)
    const int base = b * L;
    const int t    = threadIdx.x;
    const int w    = t >> 6, l = t & 63;

    const float4* laneE  = reinterpret_cast<const float4*>(isRow ? E2X : E1X);
    const float4* stripR = reinterpret_cast<const float4*>(isRow ? E1R : E2R);

    __shared__ __align__(16) float4 sstrip[4][64];   // strip E rows
    __shared__ __align__(16) float4 swst[64];        // wst
    __shared__ __align__(16) float  sS[4][L];        // unnormalized exp(S)
    __shared__ __align__(16) float4 part[4][4][64];  // PV partials

    {   // stage strip (4 rows x 256 d) + wst, coalesced
        int j = t >> 6, c = t & 63;
        sstrip[j][c] = stripR[(base + r0 + j) * 64 + c];
        if (t < 64) swst[t] = reinterpret_cast<const float4*>(wst)[t];
    }
    __syncthreads();

    // W_tot = sum(wst), computed redundantly per wave via shuffle reduce
    float W_tot;
    {
        float4 wv = swst[l];
        float s = (wv.x + wv.y) + (wv.z + wv.w);
#pragma unroll
        for (int o = 32; o; o >>= 1) s += __shfl_xor(s, o);
        W_tot = s;
    }

    // ---- score: acc[j] ~ S[strip-row j][lane-col t] ----
    float acc0 = 0.f, acc1 = 0.f, acc2 = 0.f, acc3 = 0.f;
#pragma unroll 4
    for (int d4 = 0; d4 < 64; ++d4) {
        float4 ev = laneE[d4 * 1024 + base + t];   // coalesced per-lane (L2)
        float4 s0 = sstrip[0][d4];                 // wave-uniform broadcasts
        float4 s1 = sstrip[1][d4];
        float4 s2 = sstrip[2][d4];
        float4 s3 = sstrip[3][d4];
        float4 wv = swst[d4];
        acc0 = fmaf(wv.x, fast_rcp(fmaf(ev.x, s0.x, 1.f)), acc0);
        acc0 = fmaf(wv.y, fast_rcp(fmaf(ev.y, s0.y, 1.f)), acc0);
        acc0 = fmaf(wv.z, fast_rcp(fmaf(ev.z, s0.z, 1.f)), acc0);
        acc0 = fmaf(wv.w, fast_rcp(fmaf(ev.w, s0.w, 1.f)), acc0);
        acc1 = fmaf(wv.x, fast_rcp(fmaf(ev.x, s1.x, 1.f)), acc1);
        acc1 = fmaf(wv.y, fast_rcp(fmaf(ev.y, s1.y, 1.f)), acc1);
        acc1 = fmaf(wv.z, fast_rcp(fmaf(ev.z, s1.z, 1.f)), acc1);
        acc1 = fmaf(wv.w, fast_rcp(fmaf(ev.w, s1.w, 1.f)), acc1);
        acc2 = fmaf(wv.x, fast_rcp(fmaf(ev.x, s2.x, 1.f)), acc2);
        acc2 = fmaf(wv.y, fast_rcp(fmaf(ev.y, s2.y, 1.f)), acc2);
        acc2 = fmaf(wv.z, fast_rcp(fmaf(ev.z, s2.z, 1.f)), acc2);
        acc2 = fmaf(wv.w, fast_rcp(fmaf(ev.w, s2.w, 1.f)), acc2);
        acc3 = fmaf(wv.x, fast_rcp(fmaf(ev.x, s3.x, 1.f)), acc3);
        acc3 = fmaf(wv.y, fast_rcp(fmaf(ev.y, s3.y, 1.f)), acc3);
        acc3 = fmaf(wv.z, fast_rcp(fmaf(ev.z, s3.z, 1.f)), acc3);
        acc3 = fmaf(wv.w, fast_rcp(fmaf(ev.w, s3.w, 1.f)), acc3);
    }
    float S0 = fmaf(-2.f, acc0, W_tot);
    float S1 = fmaf(-2.f, acc1, W_tot);
    float S2 = fmaf(-2.f, acc2, W_tot);
    float S3 = fmaf(-2.f, acc3, W_tot);

    if (isRow) {
        const bool dead = (mask[base + t] == 0);
        Smask[((base + r0 + 0) << 8) + t] = dead ? -1e30f : S0;
        Smask[((base + r0 + 1) << 8) + t] = dead ? -1e30f : S1;
        Smask[((base + r0 + 2) << 8) + t] = dead ? -1e30f : S2;
        Smask[((base + r0 + 3) << 8) + t] = dead ? -1e30f : S3;
        sS[0][t] = dead ? 0.f : fast_exp(S0);      // masked exp, no max needed
        sS[1][t] = dead ? 0.f : fast_exp(S1);
        sS[2][t] = dead ? 0.f : fast_exp(S2);
        sS[3][t] = dead ? 0.f : fast_exp(S3);
    } else {
        sS[0][t] = fast_exp(S0);
        sS[1][t] = fast_exp(S1);
        sS[2][t] = fast_exp(S2);
        sS[3][t] = fast_exp(S3);
    }
    __syncthreads();

    // ---- wave w: row-sum of strip-row w -> rs_w (normalizer, kept in regs)
    float rs_w;
    {
        float4 ev4 = reinterpret_cast<const float4*>(sS[w])[l];
        float s = (ev4.x + ev4.y) + (ev4.z + ev4.w);
#pragma unroll
        for (int o = 32; o; o >>= 1) s += __shfl_xor(s, o);
        rs_w = fast_rcp(s);
    }

    // ---- P @ V (unnormalized): wave w covers k in [64w,64w+64), lane l owns d4=l
    const float4* V4 = reinterpret_cast<const float4*>(isRow ? mem : x) + base * 64;
    float4 acc[4];
#pragma unroll
    for (int r = 0; r < 4; ++r) acc[r] = make_float4(0.f, 0.f, 0.f, 0.f);

#pragma unroll 2
    for (int k4 = 0; k4 < 16; ++k4) {
        const int m0 = w * 64 + k4 * 4;
        float4 v0 = V4[(m0 + 0) * 64 + l];
        float4 v1 = V4[(m0 + 1) * 64 + l];
        float4 v2 = V4[(m0 + 2) * 64 + l];
        float4 v3 = V4[(m0 + 3) * 64 + l];
#pragma unroll
        for (int r = 0; r < 4; ++r) {
            float4 pr = *reinterpret_cast<const float4*>(&sS[r][m0]);  // uniform b128
            acc[r].x = fmaf(pr.x, v0.x, acc[r].x); acc[r].y = fmaf(pr.x, v0.y, acc[r].y);
            acc[r].z = fmaf(pr.x, v0.z, acc[r].z); acc[r].w = fmaf(pr.x, v0.w, acc[r].w);
            acc[r].x = fmaf(pr.y, v1.x, acc[r].x); acc[r].y = fmaf(pr.y, v1.y, acc[r].y);
            acc[r].z = fmaf(pr.y, v1.z, acc[r].z); acc[r].w = fmaf(pr.y, v1.w, acc[r].w);
            acc[r].x = fmaf(pr.z, v2.x, acc[r].x); acc[r].y = fmaf(pr.z, v2.y, acc[r].y);
            acc[r].z = fmaf(pr.z, v2.z, acc[r].z); acc[r].w = fmaf(pr.z, v2.w, acc[r].w);
            acc[r].x = fmaf(pr.w, v3.x, acc[r].x); acc[r].y = fmaf(pr.w, v3.y, acc[r].y);
            acc[r].z = fmaf(pr.w, v3.z, acc[r].z); acc[r].w = fmaf(pr.w, v3.w, acc[r].w);
        }
    }
#pragma unroll
    for (int r = 0; r < 4; ++r) part[r][w][l] = acc[r];
    __syncthreads();

    {   // wave w reduces strip-row w, normalizes by rs_w, writes
        float4 q0 = part[w][0][l], q1 = part[w][1][l];
        float4 q2 = part[w][2][l], q3 = part[w][3][l];
        float4 ov;
        ov.x = ((q0.x + q1.x) + (q2.x + q3.x)) * rs_w;
        ov.y = ((q0.y + q1.y) + (q2.y + q3.y)) * rs_w;
        ov.z = ((q0.z + q1.z) + (q2.z + q3.z)) * rs_w;
        ov.w = ((q0.w + q1.w) + (q2.w + q3.w)) * rs_w;
        float* o = isRow ? out : agg;
        reinterpret_cast<float4*>(o)[((base + r0 + w) << 6) + l] = ov;
    }
}

extern "C" void kernel_launch(void* const* d_in, const int* in_sizes, int n_in,
                              void* d_out, int out_size, void* d_ws, size_t ws_size,
                              hipStream_t stream)
{
    const float* x    = (const float*)d_in[0];  // [4,256,256]
    const float* mem  = (const float*)d_in[1];  // [4,256,256]
    const int*   mask = (const int*)  d_in[2];  // [4,256]
    const float* w1   = (const float*)d_in[3];  // [256,256]
    const float* b1   = (const float*)d_in[4];  // [256]
    const float* w2   = (const float*)d_in[5];  // [256,256]
    const float* wst  = (const float*)d_in[6];  // [256]

    float* out   = (float*)d_out;               // [4,256,256]
    float* Smask = out + NB * L * L;            // [4,256,256] (masked S, output 1)
    float* agg   = Smask + NB * L * L;          // [4,256,256] (agg_2_h, output 2)

    float* E1X = (float*)d_ws;                  // 1 MiB each
    float* E2X = E1X + NB * L * D;
    float* E1R = E2X + NB * L * D;
    float* E2R = E1R + NB * L * D;

    linear_kernel<<<512, 256, 0, stream>>>(x, mem, w1, b1, w2, E1X, E2X, E1R, E2R);
    fused2_kernel<<<512, 256, 0, stream>>>(x, mem, mask, wst, E1X, E2X, E1R, E2R,
                                           out, Smask, agg);
}

// Round 8
// 35.445 us; speedup vs baseline: 6.8381x; 1.1765x over previous
//
#include <hip/hip_runtime.h>

static constexpr int NB = 4;    // batch
static constexpr int L  = 256;  // Lx == Lm
static constexpr int D  = 256;

__device__ __forceinline__ float fast_rcp(float x) {
#if __has_builtin(__builtin_amdgcn_rcpf)
    return __builtin_amdgcn_rcpf(x);
#else
    return 1.0f / x;
#endif
}

__device__ __forceinline__ float fast_exp(float x) {   // e^x
#if __has_builtin(__builtin_amdgcn_exp2f)
    return __builtin_amdgcn_exp2f(x * 1.4426950408889634f);
#else
    return __expf(x);
#endif
}

__device__ __forceinline__ float exp_2x(float x) {     // e^(2x)
#if __has_builtin(__builtin_amdgcn_exp2f)
    return __builtin_amdgcn_exp2f(x * 2.8853900817779268f);
#else
    return __expf(2.0f * x);
#endif
}

// ---------------------------------------------------------------------------
// K1: tiled GEMM for both linears; writes E = exp(2*(src@W^T+b)), row-major.
// Row space 0..1023 -> E1 (x,W1,b1); 1024..2047 -> E2 (mem,W2).
// Block = 32x32 tile, thread = 2x2 micro-tile.
// ---------------------------------------------------------------------------
__global__ __launch_bounds__(256) void linear_kernel(
    const float* __restrict__ x, const float* __restrict__ mem,
    const float* __restrict__ w1, const float* __restrict__ b1,
    const float* __restrict__ w2,
    float* __restrict__ E1R, float* __restrict__ E2R)
{
    const int bid = blockIdx.x;           // 512: 64 rowgroups x 8 colgroups
    const int rb  = (bid >> 3) * 32;      // 0..2047
    const int cb  = (bid & 7) * 32;
    const int which = rb >= 1024;
    const int rloc  = which ? rb - 1024 : rb;   // == b*L + row
    const float* src = which ? mem : x;
    const float* W   = which ? w2  : w1;
    float*      dstR = which ? E2R : E1R;

    constexpr int P4 = 65;
    __shared__ __align__(16) float4 xs4[32 * P4];
    __shared__ __align__(16) float4 ws4[32 * P4];

    const int t = threadIdx.x;
    const float4* src4 = reinterpret_cast<const float4*>(src) + rloc * 64;
    const float4* Wg4  = reinterpret_cast<const float4*>(W)   + cb   * 64;
#pragma unroll
    for (int k = 0; k < 8; ++k) {
        int idx = k * 256 + t;
        int r = idx >> 6, c = idx & 63;
        xs4[r * P4 + c] = src4[r * 64 + c];
        ws4[r * P4 + c] = Wg4[r * 64 + c];
    }
    __syncthreads();

    const int rr = t >> 4, cc = t & 15;   // rows {rr, rr+16}, cols {cc, cc+16}
    const float4* a0p = xs4 + rr * P4;
    const float4* a1p = xs4 + (rr + 16) * P4;
    const float4* w0p = ws4 + cc * P4;
    const float4* w1p = ws4 + (cc + 16) * P4;
    float acc00 = 0.f, acc01 = 0.f, acc10 = 0.f, acc11 = 0.f;
#pragma unroll 4
    for (int d4 = 0; d4 < 64; ++d4) {
        float4 a0 = a0p[d4], a1 = a1p[d4];
        float4 w0 = w0p[d4], w1 = w1p[d4];
        acc00 = fmaf(a0.x, w0.x, acc00); acc00 = fmaf(a0.y, w0.y, acc00);
        acc00 = fmaf(a0.z, w0.z, acc00); acc00 = fmaf(a0.w, w0.w, acc00);
        acc01 = fmaf(a0.x, w1.x, acc01); acc01 = fmaf(a0.y, w1.y, acc01);
        acc01 = fmaf(a0.z, w1.z, acc01); acc01 = fmaf(a0.w, w1.w, acc01);
        acc10 = fmaf(a1.x, w0.x, acc10); acc10 = fmaf(a1.y, w0.y, acc10);
        acc10 = fmaf(a1.z, w0.z, acc10); acc10 = fmaf(a1.w, w0.w, acc10);
        acc11 = fmaf(a1.x, w1.x, acc11); acc11 = fmaf(a1.y, w1.y, acc11);
        acc11 = fmaf(a1.z, w1.z, acc11); acc11 = fmaf(a1.w, w1.w, acc11);
    }
    const float bias0 = which ? 0.f : b1[cb + cc];
    const float bias1 = which ? 0.f : b1[cb + cc + 16];
    const int c0 = cb + cc, c1 = cb + cc + 16;
    const int rA = rloc + rr, rB = rloc + rr + 16;
    dstR[rA * D + c0] = exp_2x(acc00 + bias0);
    dstR[rA * D + c1] = exp_2x(acc01 + bias1);
    dstR[rB * D + c0] = exp_2x(acc10 + bias0);
    dstR[rB * D + c1] = exp_2x(acc11 + bias1);
}

// ---------------------------------------------------------------------------
// K2: score. 16x x 32m tile, 1x2 micro-tile. term: w*rcp(fma(e1,e2,1));
// S = W_tot - 2*acc.  Writes masked Smask + raw S^T.
// XCD swizzle: bid&7 -> (batch, xg-half) so each batch's E is L2-local.
// ---------------------------------------------------------------------------
__global__ __launch_bounds__(256) void score_kernel(
    const float* __restrict__ E1R, const float* __restrict__ E2R,
    const float* __restrict__ wst, const int* __restrict__ mask,
    float* __restrict__ Smask, float* __restrict__ ST)
{
    const int bid = blockIdx.x;           // 512
    const int p   = bid & 7, q = bid >> 3;
    const int b   = p >> 1;
    const int xg  = (q & 7) | ((p & 1) << 3);   // 0..15
    const int mg  = q >> 3;                     // 0..7
    const int xt  = xg * 16, mt = mg * 32;
    const int base = b * L;
    const int t   = threadIdx.x;

    constexpr int P4 = 65;
    __shared__ __align__(16) float4 s1[16 * P4];
    __shared__ __align__(16) float4 s2[32 * P4];
    __shared__ float stile[32 * 17];

    const float4* e14 = reinterpret_cast<const float4*>(E1R) + (base + xt) * 64;
    const float4* e24 = reinterpret_cast<const float4*>(E2R) + (base + mt) * 64;
#pragma unroll
    for (int k = 0; k < 4; ++k) {
        int idx = k * 256 + t;
        int r = idx >> 6, c = idx & 63;
        s1[r * P4 + c] = e14[r * 64 + c];
    }
#pragma unroll
    for (int k = 0; k < 8; ++k) {
        int idx = k * 256 + t;
        int r = idx >> 6, c = idx & 63;
        s2[r * P4 + c] = e24[r * 64 + c];
    }
    __syncthreads();

    const float4* w4 = reinterpret_cast<const float4*>(wst);
    float W_tot;
    {   // sum(wst) via lane-parallel read + shuffle reduce
        float4 wv = w4[t & 63];
        float s = (wv.x + wv.y) + (wv.z + wv.w);
#pragma unroll
        for (int o = 32; o; o >>= 1) s += __shfl_xor(s, o);
        W_tot = s;
    }

    const int rr = t >> 4, cc = t & 15;   // x-row rr; m-cols {cc, cc+16}
    const float4* ap  = s1 + rr * P4;
    const float4* b0p = s2 + cc * P4;
    const float4* b1p = s2 + (cc + 16) * P4;
    float acc0 = 0.f, acc1 = 0.f;
#pragma unroll 4
    for (int d4 = 0; d4 < 64; ++d4) {
        float4 a  = ap[d4];
        float4 b0 = b0p[d4], b1 = b1p[d4];
        float4 wv = w4[d4];               // uniform -> s_load
        acc0 = fmaf(wv.x, fast_rcp(fmaf(a.x, b0.x, 1.f)), acc0);
        acc0 = fmaf(wv.y, fast_rcp(fmaf(a.y, b0.y, 1.f)), acc0);
        acc0 = fmaf(wv.z, fast_rcp(fmaf(a.z, b0.z, 1.f)), acc0);
        acc0 = fmaf(wv.w, fast_rcp(fmaf(a.w, b0.w, 1.f)), acc0);
        acc1 = fmaf(wv.x, fast_rcp(fmaf(a.x, b1.x, 1.f)), acc1);
        acc1 = fmaf(wv.y, fast_rcp(fmaf(a.y, b1.y, 1.f)), acc1);
        acc1 = fmaf(wv.z, fast_rcp(fmaf(a.z, b1.z, 1.f)), acc1);
        acc1 = fmaf(wv.w, fast_rcp(fmaf(a.w, b1.w, 1.f)), acc1);
    }
    const float S0 = fmaf(-2.f, acc0, W_tot);
    const float S1 = fmaf(-2.f, acc1, W_tot);

    const int m0 = mt + cc, m1 = mt + cc + 16, x0 = xt + rr;
    Smask[((base + x0) << 8) + m0] = (mask[base + m0] == 0) ? -1e30f : S0;
    Smask[((base + x0) << 8) + m1] = (mask[base + m1] == 0) ? -1e30f : S1;

    stile[cc        * 17 + rr] = S0;      // raw S^T tile
    stile[(cc + 16) * 17 + rr] = S1;
    __syncthreads();
#pragma unroll
    for (int k = 0; k < 2; ++k) {
        int idx = k * 256 + t;
        int mr = idx >> 4, xc = idx & 15;
        ST[((base + mt + mr) << 8) + xt + xc] = stile[mr * 17 + xc];
    }
}

// ---------------------------------------------------------------------------
// K3: both attentions, 8 rows/block, 256 blocks.
// XCD swizzle: bid&7 -> (side, batch): all 32 blocks sharing one 256 KB V
// panel land on one XCD -> V stays L2-local.
// Max-free softmax (|S|<=~10; masked -1e30 -> exp=0); normalize at store.
// ---------------------------------------------------------------------------
__global__ __launch_bounds__(256) void attn_kernel(
    const float* __restrict__ x, const float* __restrict__ mem,
    const float* __restrict__ Smask, const float* __restrict__ ST,
    float* __restrict__ out, float* __restrict__ agg)
{
    const int bid  = blockIdx.x;          // 256
    const int p    = bid & 7, g = bid >> 3;
    const int side = p & 1,  b = p >> 1;
    const float* S = side ? ST : Smask;
    const float* V = side ? x  : mem;
    float*       o = side ? agg : out;
    const int base = b * L;
    const int row0 = g * 8;
    const int t = threadIdx.x, w = t >> 6, l = t & 63;

    __shared__ __align__(16) float  ps[8][L];        // exp(S), unnormalized
    __shared__ __align__(16) float4 part[8][4][64];  // PV partials

    // exp pass: wave w owns rows {w, w+4}; keep row-sum reciprocals in regs
    float rs0, rs1;
#pragma unroll
    for (int rr = w, it = 0; rr < 8; rr += 4, ++it) {
        float4 sv = reinterpret_cast<const float4*>(S)[((base + row0 + rr) << 6) + l];
        float e0 = fast_exp(sv.x), e1 = fast_exp(sv.y);
        float e2 = fast_exp(sv.z), e3 = fast_exp(sv.w);
        reinterpret_cast<float4*>(ps[rr])[l] = make_float4(e0, e1, e2, e3);
        float s = (e0 + e1) + (e2 + e3);
#pragma unroll
        for (int off = 32; off; off >>= 1) s += __shfl_xor(s, off);
        if (it == 0) rs0 = fast_rcp(s); else rs1 = fast_rcp(s);
    }
    __syncthreads();

    // P @ V: wave w covers k in [64w,64w+64), lane l owns d4=l
    const float4* V4 = reinterpret_cast<const float4*>(V) + base * 64;
    float4 acc[8];
#pragma unroll
    for (int r = 0; r < 8; ++r) acc[r] = make_float4(0.f, 0.f, 0.f, 0.f);

#pragma unroll 2
    for (int k4 = 0; k4 < 16; ++k4) {
        const int m0 = w * 64 + k4 * 4;
        float4 v0 = V4[(m0 + 0) * 64 + l];
        float4 v1 = V4[(m0 + 1) * 64 + l];
        float4 v2 = V4[(m0 + 2) * 64 + l];
        float4 v3 = V4[(m0 + 3) * 64 + l];
#pragma unroll
        for (int r = 0; r < 8; ++r) {
            float4 pr = *reinterpret_cast<const float4*>(&ps[r][m0]);  // uniform b128
            acc[r].x = fmaf(pr.x, v0.x, acc[r].x); acc[r].y = fmaf(pr.x, v0.y, acc[r].y);
            acc[r].z = fmaf(pr.x, v0.z, acc[r].z); acc[r].w = fmaf(pr.x, v0.w, acc[r].w);
            acc[r].x = fmaf(pr.y, v1.x, acc[r].x); acc[r].y = fmaf(pr.y, v1.y, acc[r].y);
            acc[r].z = fmaf(pr.y, v1.z, acc[r].z); acc[r].w = fmaf(pr.y, v1.w, acc[r].w);
            acc[r].x = fmaf(pr.z, v2.x, acc[r].x); acc[r].y = fmaf(pr.z, v2.y, acc[r].y);
            acc[r].z = fmaf(pr.z, v2.z, acc[r].z); acc[r].w = fmaf(pr.z, v2.w, acc[r].w);
            acc[r].x = fmaf(pr.w, v3.x, acc[r].x); acc[r].y = fmaf(pr.w, v3.y, acc[r].y);
            acc[r].z = fmaf(pr.w, v3.z, acc[r].z); acc[r].w = fmaf(pr.w, v3.w, acc[r].w);
        }
    }
#pragma unroll
    for (int r = 0; r < 8; ++r) part[r][w][l] = acc[r];
    __syncthreads();

    // reduce: wave w handles rows {w, w+4}, normalize, store
#pragma unroll
    for (int rr = w, it = 0; rr < 8; rr += 4, ++it) {
        float rs = (it == 0) ? rs0 : rs1;
        float4 q0 = part[rr][0][l], q1 = part[rr][1][l];
        float4 q2 = part[rr][2][l], q3 = part[rr][3][l];
        float4 ov;
        ov.x = ((q0.x + q1.x) + (q2.x + q3.x)) * rs;
        ov.y = ((q0.y + q1.y) + (q2.y + q3.y)) * rs;
        ov.z = ((q0.z + q1.z) + (q2.z + q3.z)) * rs;
        ov.w = ((q0.w + q1.w) + (q2.w + q3.w)) * rs;
        reinterpret_cast<float4*>(o)[((base + row0 + rr) << 6) + l] = ov;
    }
}

extern "C" void kernel_launch(void* const* d_in, const int* in_sizes, int n_in,
                              void* d_out, int out_size, void* d_ws, size_t ws_size,
                              hipStream_t stream)
{
    const float* x    = (const float*)d_in[0];  // [4,256,256]
    const float* mem  = (const float*)d_in[1];  // [4,256,256]
    const int*   mask = (const int*)  d_in[2];  // [4,256]
    const float* w1   = (const float*)d_in[3];  // [256,256]
    const float* b1   = (const float*)d_in[4];  // [256]
    const float* w2   = (const float*)d_in[5];  // [256,256]
    const float* wst  = (const float*)d_in[6];  // [256]

    float* out   = (float*)d_out;               // [4,256,256]
    float* Smask = out + NB * L * L;            // [4,256,256] (masked S, output 1)
    float* agg   = Smask + NB * L * L;          // [4,256,256] (agg_2_h, output 2)

    float* E1R = (float*)d_ws;                  // 1 MiB each
    float* E2R = E1R + NB * L * D;
    float* ST  = E2R + NB * L * D;              // raw S^T

    linear_kernel<<<512, 256, 0, stream>>>(x, mem, w1, b1, w2, E1R, E2R);
    score_kernel<<<512, 256, 0, stream>>>(E1R, E2R, wst, mask, Smask, ST);
    attn_kernel<<<256, 256, 0, stream>>>(x, mem, Smask, ST, out, agg);
}